// Round 7
// baseline (149.731 us; speedup 1.0000x reference)
//
#include <hip/hip_runtime.h>

#define BB 512
#define DD 128
#define HD 64

typedef float v2f __attribute__((ext_vector_type(2)));
#define FMA2(a, b, c) __builtin_elementwise_fma((v2f)(a), (v2f)(b), (v2f)(c))

// ---- workspace layout (float offsets) ----
#define OFF_E1 0                     // 3 * 512 * 128  (normalized emb1, packed (d, d+64))
#define OFF_E2 (3*BB*DD)             // 3 * 512 * 128
#define OFF_C1 (2*3*BB*DD)           // 2 * 512 * 128  (cert1 layers 1,2 packed)
#define OFF_C2 (OFF_C1 + 2*BB*DD)    // 2 * 512 * 128
#define OFF_AB (OFF_C2 + 2*BB*DD)    // 2 layers * (A[128], B[128]); A=-log2e*alpha, B=-log2e*beta
#define OFF_LNK (OFF_AB + 512)       // 2 links * (idx[3][128], w[3][128]) = 2*768
// precomputed layer-1 gather factors (link-0 only, row-dependent):
#define OFF_UG (OFF_LNK + 1536)      // 512*3*128: i-side -2*w1k*u0[idx1k], packed (e,e+64)
#define OFF_SU (OFF_UG + 3*BB*DD)    // 512*128:   sum_k w1k*u0[idx1k]^2
#define OFF_VG (OFF_SU + BB*DD)      // 512*3*128: j-side v0[idx1k]
#define OFF_SV (OFF_VG + 3*BB*DD)    // 512*128
#define WS_FLOATS (OFF_SV + BB*DD)   // ~4.5 MB

__device__ __forceinline__ float wave_sum64(float v) {
  #pragma unroll
  for (int off = 1; off < 64; off <<= 1) v += __shfl_xor(v, off, 64);
  return v;
}

// DPP lane-shift add: pure VALU pipe. Sum of all 64 lanes lands in lane 63.
template <int CTRL>
__device__ __forceinline__ float dpp_mov(float x) {
  int i = __builtin_bit_cast(int, x);
  int r = __builtin_amdgcn_update_dpp(0, i, CTRL, 0xF, 0xF, false);
  return __builtin_bit_cast(float, r);
}
__device__ __forceinline__ float dpp_wave_sum_lane63(float v) {
  v += dpp_mov<0x111>(v);  // row_shr:1
  v += dpp_mov<0x112>(v);  // row_shr:2
  v += dpp_mov<0x114>(v);  // row_shr:4
  v += dpp_mov<0x118>(v);  // row_shr:8
  v += dpp_mov<0x142>(v);  // row_bcast:15
  v += dpp_mov<0x143>(v);  // row_bcast:31
  return v;
}

// lane-pull: result.lane = src[(addr>>2)&63]; addr precomputed byte address
__device__ __forceinline__ float bperm(int addr, float src) {
  int r = __builtin_amdgcn_ds_bpermute(addr, __builtin_bit_cast(int, src));
  return __builtin_bit_cast(float, r);
}

// ---- prep 1: links first, then normalize/pack.
// link-0 indices stored as interleaved LDS words 2c+h (for prep2's plane
// gather); link-1 indices stored RAW (0..127) for main's bpermute gather.
struct PackArgs { const float* src[10]; };

__global__ __launch_bounds__(256) void prep_kernel(PackArgs a,
                                                   const float* __restrict__ lnk0,
                                                   const float* __restrict__ lnk1,
                                                   const float* __restrict__ a1,
                                                   const float* __restrict__ b1,
                                                   const float* __restrict__ a2,
                                                   const float* __restrict__ b2,
                                                   float* __restrict__ ws) {
  const int tid  = threadIdx.x;
  const int lane = tid & 63;
  if (blockIdx.x >= 64) {
    const int gw   = (blockIdx.x - 64) * 4 + (tid >> 6);
    const int arr  = gw >> 9;                       // 0..9
    const int row  = gw & 511;
    const float* s = a.src[arr];
    float lo = s[row * DD + lane];
    float hi = s[row * DD + lane + 64];
    float scale = 1.0f;
    if (arr < 6) {  // embeddings: L2 normalize
      float ss = wave_sum64(lo * lo + hi * hi);
      scale = 1.0f / fmaxf(sqrtf(ss), 1e-12f);
    }
    float* dst;
    if (arr < 3)      dst = ws + OFF_E1 + arr * (BB * DD);
    else if (arr < 6) dst = ws + OFF_E2 + (arr - 3) * (BB * DD);
    else if (arr < 8) dst = ws + OFF_C1 + (arr - 6) * (BB * DD);
    else              dst = ws + OFF_C2 + (arr - 8) * (BB * DD);
    ((float2*)dst)[row * HD + lane] = make_float2(lo * scale, hi * scale);
  } else {
    // one wave per (l, e) column; lane d holds L[d][e] and L[d+64][e]
    const int task = blockIdx.x * 4 + (tid >> 6);   // 0..255
    const int l = task >> 7, e = task & 127;
    const float* L = l ? lnk1 : lnk0;
    float v0 = L[lane * DD + e];
    float v1 = L[(lane + 64) * DD + e];
    float bv[3]; int bd[3];
    #pragma unroll
    for (int k = 0; k < 3; ++k) {
      float lv; int ld;
      if (v0 >= v1) { lv = v0; ld = lane; } else { lv = v1; ld = lane + 64; }
      #pragma unroll
      for (int off = 1; off < 64; off <<= 1) {
        float ov = __shfl_xor(lv, off, 64);
        int   od = __shfl_xor(ld, off, 64);
        if (ov > lv || (ov == lv && od < ld)) { lv = ov; ld = od; }
      }
      bv[k] = lv; bd[k] = ld;             // same in all lanes
      if (ld == lane)      v0 = -1e30f;   // remove winner
      if (ld == lane + 64) v1 = -1e30f;
    }
    if (lane == 0) {
      float inv = 1.0f / (bv[0] + bv[1] + bv[2] + 1e-8f);
      int*   li = (int*)(ws + OFF_LNK + l * 768);
      float* lw =        ws + OFF_LNK + l * 768 + 384;
      if (l == 0) {
        // dim d -> interleaved LDS word ((d&63)<<1) | (d>>6) = 2c + h
        li[e]       = ((bd[0] & 63) << 1) | (bd[0] >> 6);
        li[128 + e] = ((bd[1] & 63) << 1) | (bd[1] >> 6);
        li[256 + e] = ((bd[2] & 63) << 1) | (bd[2] >> 6);
      } else {
        // RAW dims for main's register bpermute gather
        li[e] = bd[0]; li[128 + e] = bd[1]; li[256 + e] = bd[2];
      }
      lw[e] = bv[0] * inv; lw[128 + e] = bv[1] * inv; lw[256 + e] = bv[2] * inv;
      const float NL2E = -1.4426950408889634f;
      const float* al = l ? a2 : a1;
      const float* bl = l ? b2 : b1;
      ws[OFF_AB + l * 256 + e]       = NL2E * al[e];
      ws[OFF_AB + l * 256 + 128 + e] = NL2E * bl[e];
    }
  }
}

// ---- prep 2 (verified bit-exact): hoist ALL layer-1 (link-0) gathers.
__global__ __launch_bounds__(256) void prep2_kernel(float* __restrict__ ws) {
  __shared__ float pl[4][DD];
  const int tid  = threadIdx.x;
  const int lane = tid & 63;
  const int w    = tid >> 6;
  float*  p  = pl[w];
  float2* p2 = (float2*)p;
  const int gw   = blockIdx.x * 4 + w;   // 0..1023
  const int side = gw >> 9;              // 0: emb1 (U-side), 1: emb2 (V-side)
  const int row  = gw & 511;
  const int*   li0 = (const int*)(ws + OFF_LNK);
  const float* lw0 = ws + OFF_LNK + 384;
  int I[3][2]; v2f W[3];
  #pragma unroll
  for (int k = 0; k < 3; ++k) {
    I[k][0] = li0[k * 128 + lane]; I[k][1] = li0[k * 128 + lane + 64];
    W[k].x  = lw0[k * 128 + lane]; W[k].y  = lw0[k * 128 + lane + 64];
  }
  const float2* Ep = (const float2*)(ws + (side ? OFF_E2 : OFF_E1));
  float2 u0 = Ep[row * HD + lane];       // normalized layer-0 row (from prep1)
  p2[lane] = u0;                         // same-wave DS: in-order, no barrier
  v2f S = (v2f)0.0f; v2f G[3];
  #pragma unroll
  for (int k = 0; k < 3; ++k) {
    v2f a; a.x = p[I[k][0]]; a.y = p[I[k][1]];
    v2f t = W[k] * a;
    S = FMA2(t, a, S);                   // sum_k w_k * x[d_k]^2
    G[k] = side ? a : (-2.0f * t);       // V-side: raw gather; U-side: -2*w_k*u0[d_k]
  }
  float2* Gp = (float2*)(ws + (side ? OFF_VG : OFF_UG));
  float2* Sp = (float2*)(ws + (side ? OFF_SV : OFF_SU));
  #pragma unroll
  for (int k = 0; k < 3; ++k) Gp[(row * 3 + k) * HD + lane] = make_float2(G[k].x, G[k].y);
  Sp[row * HD + lane] = make_float2(S.x, S.y);
}

// ---- main (R19): layer-2 gather via ds_bpermute on REGISTER h1 — the LDS
// round-trip (write -> 6 conflicted reads -> lgkmcnt -> consume, ~120-150 cy
// serial per output) is deleted. R16/R17 showed conflicts aren't the cost;
// R15/R18 wave-duty arithmetic (VALU 50% / 2.6 resident = 19% duty) showed
// the round-trip LATENCY is. bpermute pulls lane (addr>>2)&63 from a register
// operand: no write, no memory RAW, no bank conflicts, and no LDS fence — the
// compiler is free to interleave the 4 independent ii-chains itself.
// Gather: source dim d -> lane d&63, component d>>6 (h1.x=dim lane, .y=lane+64);
// per gather 2 bpermutes + 1 cndmask (bool hoisted to SGPR-pair mask).
// Config = R15 (verified best 43.7 us): ii=4, jj=8, grid 2048, (256,4).
__global__ __launch_bounds__(256, 4) void main_kernel(const float* __restrict__ ws,
                                                      float* __restrict__ out) {
  const int tid  = threadIdx.x;
  const int lane = tid & 63;
  const int w    = tid >> 6;
  const int gw = blockIdx.x * 4 + w;     // 8192 waves
  const int i0 = (gw >> 6) * 4;          // 128 i-tiles of 4
  const int j0 = (gw & 63) * 8;          // 64 j-chunks of 8

  const int*   li1 = (const int*)(ws + OFF_LNK + 768);   // RAW dims
  const float* lw1 = ws + OFF_LNK + 768 + 384;
  int  ax[3], ay[3];     // bpermute byte addrs for x-outputs (e=lane) / y-outputs (e=lane+64)
  bool hx[3], hy[3];     // component selects (d>=64 -> take .y)
  v2f W2[3];
  #pragma unroll
  for (int k = 0; k < 3; ++k) {
    int dx = li1[k * 128 + lane];
    int dy = li1[k * 128 + lane + 64];
    ax[k] = (dx & 63) << 2; hx[k] = dx >= 64;
    ay[k] = (dy & 63) << 2; hy[k] = dy >= 64;
    W2[k].x = lw1[k * 128 + lane]; W2[k].y = lw1[k * 128 + lane + 64];
  }
  v2f Av1, Bv1, Av2, Bv2;
  Av1.x = ws[OFF_AB + lane];       Av1.y = ws[OFF_AB + lane + 64];
  Bv1.x = ws[OFF_AB + 128 + lane]; Bv1.y = ws[OFF_AB + 128 + lane + 64];
  Av2.x = ws[OFF_AB + 256 + lane]; Av2.y = ws[OFF_AB + 256 + lane + 64];
  Bv2.x = ws[OFF_AB + 384 + lane]; Bv2.y = ws[OFF_AB + 384 + lane + 64];

  const float2* E1p = (const float2*)(ws + OFF_E1);
  const float2* E2p = (const float2*)(ws + OFF_E2);
  const float2* C1p = (const float2*)(ws + OFF_C1);
  const float2* C2p = (const float2*)(ws + OFF_C2);
  const float2* UGp = (const float2*)(ws + OFF_UG);
  const float2* SUp = (const float2*)(ws + OFF_SU);
  const float2* VGp = (const float2*)(ws + OFF_VG);
  const float2* SVp = (const float2*)(ws + OFF_SV);
  #define LD2(p, idx) ({ float2 _t = (p)[idx]; v2f _v; _v.x = _t.x; _v.y = _t.y; _v; })

  // i-tile state (amortized over 8 j's)
  v2f ug[4][3], su[4], u1[4], u2[4], c11[4], c12[4];
  #pragma unroll
  for (int ii = 0; ii < 4; ++ii) {
    const int i = i0 + ii;
    #pragma unroll
    for (int k = 0; k < 3; ++k) ug[ii][k] = LD2(UGp, (i * 3 + k) * HD + lane);
    su[ii]  = LD2(SUp, i * HD + lane);
    u1[ii]  = LD2(E1p, (1 * BB + i) * HD + lane);
    u2[ii]  = LD2(E1p, (2 * BB + i) * HD + lane);
    c11[ii] = LD2(C1p, (0 * BB + i) * HD + lane);
    c12[ii] = LD2(C1p, (1 * BB + i) * HD + lane);
  }

  #pragma unroll 1
  for (int jj = 0; jj < 8; ++jj) {
    const int j = j0 + jj;
    v2f vg0  = LD2(VGp, (j * 3 + 0) * HD + lane);
    v2f vg1  = LD2(VGp, (j * 3 + 1) * HD + lane);
    v2f vg2v = LD2(VGp, (j * 3 + 2) * HD + lane);
    v2f sv   = LD2(SVp, j * HD + lane);
    const v2f v1  = LD2(E2p, (1 * BB + j) * HD + lane);
    const v2f v2  = LD2(E2p, (2 * BB + j) * HD + lane);
    const v2f g21 = LD2(C2p, (0 * BB + j) * HD + lane);
    const v2f g22 = LD2(C2p, (1 * BB + j) * HD + lane);
    #pragma unroll
    for (int ii = 0; ii < 4; ++ii) {
      // layer 1: g from precomputed factored gathers (registers only, pk-fma)
      v2f g1 = FMA2(ug[ii][0], vg0, FMA2(ug[ii][1], vg1,
                FMA2(ug[ii][2], vg2v, su[ii] + sv)));
      v2f d1 = u1[ii] - v1;
      v2f n1 = d1 * d1;
      v2f x1 = FMA2(c11[ii] * g21, Av1, Bv1);
      v2f t1, P1;
      t1.x = __builtin_amdgcn_exp2f(x1.x); t1.y = __builtin_amdgcn_exp2f(x1.y);
      P1.x = __builtin_amdgcn_rcpf(1.0f + t1.x); P1.y = __builtin_amdgcn_rcpf(1.0f + t1.y);
      v2f h1 = FMA2(P1, n1 - g1, g1);           // (1-P)*g + P*n
      // layer 2: register gather via ds_bpermute (no LDS storage)
      float q0, q1, q2, q3, q4, q5;
      {
        float px, py;
        px = bperm(ax[0], h1.x); py = bperm(ax[0], h1.y); q0 = hx[0] ? py : px;
        px = bperm(ax[1], h1.x); py = bperm(ax[1], h1.y); q1 = hx[1] ? py : px;
        px = bperm(ax[2], h1.x); py = bperm(ax[2], h1.y); q2 = hx[2] ? py : px;
        px = bperm(ay[0], h1.x); py = bperm(ay[0], h1.y); q3 = hy[0] ? py : px;
        px = bperm(ay[1], h1.x); py = bperm(ay[1], h1.y); q4 = hy[1] ? py : px;
        px = bperm(ay[2], h1.x); py = bperm(ay[2], h1.y); q5 = hy[2] ? py : px;
      }
      v2f g2;
      g2.x = q0 * W2[0].x + q1 * W2[1].x + q2 * W2[2].x;
      g2.y = q3 * W2[0].y + q4 * W2[1].y + q5 * W2[2].y;
      v2f d2 = u2[ii] - v2;
      v2f n2 = d2 * d2;
      v2f x2 = FMA2(c12[ii] * g22, Av2, Bv2);
      v2f t2, P2;
      t2.x = __builtin_amdgcn_exp2f(x2.x); t2.y = __builtin_amdgcn_exp2f(x2.y);
      P2.x = __builtin_amdgcn_rcpf(1.0f + t2.x); P2.y = __builtin_amdgcn_rcpf(1.0f + t2.y);
      v2f h2 = FMA2(P2, n2 - g2, g2);
      // reduce over 128 dims: DPP (VALU pipe), sum lands in lane 63
      float s = dpp_wave_sum_lane63(h2.x + h2.y);
      if (lane == 63) out[(i0 + ii) * BB + j] = s;
    }
  }
}

extern "C" void kernel_launch(void* const* d_in, const int* in_sizes, int n_in,
                              void* d_out, int out_size, void* d_ws, size_t ws_size,
                              hipStream_t stream) {
  (void)in_sizes; (void)n_in; (void)out_size; (void)ws_size;
  // dict order: [0]emb1_0 [1]emb2_0 [2]cert1_0 [3]cert2_0 [4]alpha_0 [5]beta_0
  //             [6..11] layer1, [12..17] layer2, [18]link_0 [19]link_1
  float* ws = (float*)d_ws;
  PackArgs pa;
  pa.src[0] = (const float*)d_in[0];  pa.src[1] = (const float*)d_in[6];  pa.src[2] = (const float*)d_in[12];
  pa.src[3] = (const float*)d_in[1];  pa.src[4] = (const float*)d_in[7];  pa.src[5] = (const float*)d_in[13];
  pa.src[6] = (const float*)d_in[8];  pa.src[7] = (const float*)d_in[14];
  pa.src[8] = (const float*)d_in[9];  pa.src[9] = (const float*)d_in[15];
  hipLaunchKernelGGL(prep_kernel, dim3(1344), dim3(256), 0, stream, pa,
                     (const float*)d_in[18], (const float*)d_in[19],
                     (const float*)d_in[10], (const float*)d_in[11],
                     (const float*)d_in[16], (const float*)d_in[17], ws);
  hipLaunchKernelGGL(prep2_kernel, dim3(256), dim3(256), 0, stream, ws);
  hipLaunchKernelGGL(main_kernel, dim3(2048), dim3(256), 0, stream,
                     (const float*)ws, (float*)d_out);
}

// Round 8
// 143.167 us; speedup vs baseline: 1.0458x; 1.0458x over previous
//
#include <hip/hip_runtime.h>

#define BB 512
#define DD 128
#define HD 64

typedef float v2f __attribute__((ext_vector_type(2)));
#define FMA2(a, b, c) __builtin_elementwise_fma((v2f)(a), (v2f)(b), (v2f)(c))

// ---- workspace layout (float offsets) ----
#define OFF_E1 0                     // 3 * 512 * 128  (normalized emb1, packed (d, d+64))
#define OFF_E2 (3*BB*DD)             // 3 * 512 * 128
#define OFF_C1 (2*3*BB*DD)           // 2 * 512 * 128  (cert1 layers 1,2 packed)
#define OFF_C2 (OFF_C1 + 2*BB*DD)    // 2 * 512 * 128
#define OFF_AB (OFF_C2 + 2*BB*DD)    // 2 layers * (A[128], B[128]); A=-log2e*alpha, B=-log2e*beta
#define OFF_LNK (OFF_AB + 512)       // 2 links * (idx[3][128] interleaved, w[3][128]) = 2*768
// precomputed layer-1 gather factors (link-0 only, row-dependent):
#define OFF_UG (OFF_LNK + 1536)      // 512*3*128: i-side -2*w1k*u0[idx1k], packed (e,e+64)
#define OFF_SU (OFF_UG + 3*BB*DD)    // 512*128:   sum_k w1k*u0[idx1k]^2
#define OFF_VG (OFF_SU + BB*DD)      // 512*3*128: j-side v0[idx1k]
#define OFF_SV (OFF_VG + 3*BB*DD)    // 512*128
#define WS_FLOATS (OFF_SV + BB*DD)   // ~4.5 MB

__device__ __forceinline__ float wave_sum64(float v) {
  #pragma unroll
  for (int off = 1; off < 64; off <<= 1) v += __shfl_xor(v, off, 64);
  return v;
}

// DPP lane-shift add: pure VALU pipe. Sum of all 64 lanes lands in lane 63.
template <int CTRL>
__device__ __forceinline__ float dpp_mov(float x) {
  int i = __builtin_bit_cast(int, x);
  int r = __builtin_amdgcn_update_dpp(0, i, CTRL, 0xF, 0xF, false);
  return __builtin_bit_cast(float, r);
}
__device__ __forceinline__ float dpp_wave_sum_lane63(float v) {
  v += dpp_mov<0x111>(v);  // row_shr:1
  v += dpp_mov<0x112>(v);  // row_shr:2
  v += dpp_mov<0x114>(v);  // row_shr:4
  v += dpp_mov<0x118>(v);  // row_shr:8
  v += dpp_mov<0x142>(v);  // row_bcast:15
  v += dpp_mov<0x143>(v);  // row_bcast:31
  return v;
}

// ---- prep 1 (identical to R15): links first, then normalize/pack. Both
// links stored as interleaved indices 2c+h (dim d -> 2*(d&63) + (d>>6)). ----
struct PackArgs { const float* src[10]; };

__global__ __launch_bounds__(256) void prep_kernel(PackArgs a,
                                                   const float* __restrict__ lnk0,
                                                   const float* __restrict__ lnk1,
                                                   const float* __restrict__ a1,
                                                   const float* __restrict__ b1,
                                                   const float* __restrict__ a2,
                                                   const float* __restrict__ b2,
                                                   float* __restrict__ ws) {
  const int tid  = threadIdx.x;
  const int lane = tid & 63;
  if (blockIdx.x >= 64) {
    const int gw   = (blockIdx.x - 64) * 4 + (tid >> 6);
    const int arr  = gw >> 9;                       // 0..9
    const int row  = gw & 511;
    const float* s = a.src[arr];
    float lo = s[row * DD + lane];
    float hi = s[row * DD + lane + 64];
    float scale = 1.0f;
    if (arr < 6) {  // embeddings: L2 normalize
      float ss = wave_sum64(lo * lo + hi * hi);
      scale = 1.0f / fmaxf(sqrtf(ss), 1e-12f);
    }
    float* dst;
    if (arr < 3)      dst = ws + OFF_E1 + arr * (BB * DD);
    else if (arr < 6) dst = ws + OFF_E2 + (arr - 3) * (BB * DD);
    else if (arr < 8) dst = ws + OFF_C1 + (arr - 6) * (BB * DD);
    else              dst = ws + OFF_C2 + (arr - 8) * (BB * DD);
    ((float2*)dst)[row * HD + lane] = make_float2(lo * scale, hi * scale);
  } else {
    // one wave per (l, e) column; lane d holds L[d][e] and L[d+64][e]
    const int task = blockIdx.x * 4 + (tid >> 6);   // 0..255
    const int l = task >> 7, e = task & 127;
    const float* L = l ? lnk1 : lnk0;
    float v0 = L[lane * DD + e];
    float v1 = L[(lane + 64) * DD + e];
    float bv[3]; int bd[3];
    #pragma unroll
    for (int k = 0; k < 3; ++k) {
      float lv; int ld;
      if (v0 >= v1) { lv = v0; ld = lane; } else { lv = v1; ld = lane + 64; }
      #pragma unroll
      for (int off = 1; off < 64; off <<= 1) {
        float ov = __shfl_xor(lv, off, 64);
        int   od = __shfl_xor(ld, off, 64);
        if (ov > lv || (ov == lv && od < ld)) { lv = ov; ld = od; }
      }
      bv[k] = lv; bd[k] = ld;             // same in all lanes
      if (ld == lane)      v0 = -1e30f;   // remove winner
      if (ld == lane + 64) v1 = -1e30f;
    }
    if (lane == 0) {
      float inv = 1.0f / (bv[0] + bv[1] + bv[2] + 1e-8f);
      int*   li = (int*)(ws + OFF_LNK + l * 768);
      float* lw =        ws + OFF_LNK + l * 768 + 384;
      // dim d -> interleaved index ((d&63)<<1) | (d>>6) = 2c + h
      li[e]       = ((bd[0] & 63) << 1) | (bd[0] >> 6);
      li[128 + e] = ((bd[1] & 63) << 1) | (bd[1] >> 6);
      li[256 + e] = ((bd[2] & 63) << 1) | (bd[2] >> 6);
      lw[e] = bv[0] * inv; lw[128 + e] = bv[1] * inv; lw[256 + e] = bv[2] * inv;
      const float NL2E = -1.4426950408889634f;
      const float* al = l ? a2 : a1;
      const float* bl = l ? b2 : b1;
      ws[OFF_AB + l * 256 + e]       = NL2E * al[e];
      ws[OFF_AB + l * 256 + 128 + e] = NL2E * bl[e];
    }
  }
}

// ---- prep 2 (verified bit-exact, unchanged): hoist ALL layer-1 gathers.
__global__ __launch_bounds__(256) void prep2_kernel(float* __restrict__ ws) {
  __shared__ float pl[4][DD];
  const int tid  = threadIdx.x;
  const int lane = tid & 63;
  const int w    = tid >> 6;
  float*  p  = pl[w];
  float2* p2 = (float2*)p;
  const int gw   = blockIdx.x * 4 + w;   // 0..1023
  const int side = gw >> 9;              // 0: emb1 (U-side), 1: emb2 (V-side)
  const int row  = gw & 511;
  const int*   li0 = (const int*)(ws + OFF_LNK);
  const float* lw0 = ws + OFF_LNK + 384;
  int I[3][2]; v2f W[3];
  #pragma unroll
  for (int k = 0; k < 3; ++k) {
    I[k][0] = li0[k * 128 + lane]; I[k][1] = li0[k * 128 + lane + 64];
    W[k].x  = lw0[k * 128 + lane]; W[k].y  = lw0[k * 128 + lane + 64];
  }
  const float2* Ep = (const float2*)(ws + (side ? OFF_E2 : OFF_E1));
  float2 u0 = Ep[row * HD + lane];       // normalized layer-0 row (from prep1)
  p2[lane] = u0;                         // same-wave DS: in-order, no barrier
  v2f S = (v2f)0.0f; v2f G[3];
  #pragma unroll
  for (int k = 0; k < 3; ++k) {
    v2f a; a.x = p[I[k][0]]; a.y = p[I[k][1]];
    v2f t = W[k] * a;
    S = FMA2(t, a, S);                   // sum_k w_k * x[d_k]^2
    G[k] = side ? a : (-2.0f * t);       // V-side: raw gather; U-side: -2*w_k*u0[d_k]
  }
  float2* Gp = (float2*)(ws + (side ? OFF_VG : OFF_UG));
  float2* Sp = (float2*)(ws + (side ? OFF_SV : OFF_SU));
  #pragma unroll
  for (int k = 0; k < 3; ++k) Gp[(row * 3 + k) * HD + lane] = make_float2(G[k].x, G[k].y);
  Sp[row * HD + lane] = make_float2(S.x, S.y);
}

// ---- main (R20): PAIRED-PLANE gather — 2 outputs share the 6 gather reads.
// R19 measured the DS-pipe marginal cost: +5 DS ops/output = +16 us (~3 us
// per DS op/output); DS op COUNT is the critical path (conflicts counter also
// fires on LDS-free bpermute -> it's generic DS serialization, not avoidable
// collisions). Gather ADDRESSES are static per lane; only h1 data varies per
// pair. So: interleave two h1 planes word-wise — dim d, plane p at word
// 4(d&63)+2(d>>6)+p — and one ds_read_b64 at float2-slot 2(d&63)+(d>>6)
// (same index prep already stores!) fetches the gathered value for BOTH
// planes. ii processed in pairs: 2 h1-computes, 2 writes (2xb32 each), 6
// shared b64 reads, 2 consumes. DS/output: 7 -> 4; lgkmcnt waits halve and
// get a full h1-VALU phase of slack. Arithmetic bit-identical (absmax 0.0).
// Config = R15 verified best: ii=4, jj=8, grid 2048, (256,4).
__global__ __launch_bounds__(256, 4) void main_kernel(const float* __restrict__ ws,
                                                      float* __restrict__ out) {
  __shared__ float hbuf[4][2 * DD];      // per-wave paired plane: 256 words
  const int tid  = threadIdx.x;
  const int lane = tid & 63;
  const int w    = tid >> 6;
  float*        hb  = hbuf[w];
  const float2* hb2 = (const float2*)hb; // slot s=2c+h -> (plane0, plane1) of dim d
  const int gw = blockIdx.x * 4 + w;     // 8192 waves
  const int i0 = (gw >> 6) * 4;          // 128 i-tiles of 4
  const int j0 = (gw & 63) * 8;          // 64 j-chunks of 8

  const int*   li1 = (const int*)(ws + OFF_LNK + 768);
  const float* lw1 = ws + OFF_LNK + 768 + 384;
  int I2[3][2]; v2f W2[3];
  #pragma unroll
  for (int k = 0; k < 3; ++k) {
    I2[k][0] = li1[k * 128 + lane]; I2[k][1] = li1[k * 128 + lane + 64];
    W2[k].x  = lw1[k * 128 + lane]; W2[k].y  = lw1[k * 128 + lane + 64];
  }
  v2f Av1, Bv1, Av2, Bv2;
  Av1.x = ws[OFF_AB + lane];       Av1.y = ws[OFF_AB + lane + 64];
  Bv1.x = ws[OFF_AB + 128 + lane]; Bv1.y = ws[OFF_AB + 128 + lane + 64];
  Av2.x = ws[OFF_AB + 256 + lane]; Av2.y = ws[OFF_AB + 256 + lane + 64];
  Bv2.x = ws[OFF_AB + 384 + lane]; Bv2.y = ws[OFF_AB + 384 + lane + 64];

  const float2* E1p = (const float2*)(ws + OFF_E1);
  const float2* E2p = (const float2*)(ws + OFF_E2);
  const float2* C1p = (const float2*)(ws + OFF_C1);
  const float2* C2p = (const float2*)(ws + OFF_C2);
  const float2* UGp = (const float2*)(ws + OFF_UG);
  const float2* SUp = (const float2*)(ws + OFF_SU);
  const float2* VGp = (const float2*)(ws + OFF_VG);
  const float2* SVp = (const float2*)(ws + OFF_SV);
  #define LD2(p, idx) ({ float2 _t = (p)[idx]; v2f _v; _v.x = _t.x; _v.y = _t.y; _v; })

  // i-tile state (amortized over 8 j's)
  v2f ug[4][3], su[4], u1[4], u2[4], c11[4], c12[4];
  #pragma unroll
  for (int ii = 0; ii < 4; ++ii) {
    const int i = i0 + ii;
    #pragma unroll
    for (int k = 0; k < 3; ++k) ug[ii][k] = LD2(UGp, (i * 3 + k) * HD + lane);
    su[ii]  = LD2(SUp, i * HD + lane);
    u1[ii]  = LD2(E1p, (1 * BB + i) * HD + lane);
    u2[ii]  = LD2(E1p, (2 * BB + i) * HD + lane);
    c11[ii] = LD2(C1p, (0 * BB + i) * HD + lane);
    c12[ii] = LD2(C1p, (1 * BB + i) * HD + lane);
  }

  // H1 phase for pair-plane p: compute h1, write dim words 4*lane+p (x) and
  // 4*lane+2+p (y). In-order DS pipe: no fence needed within the wave.
  #define H1PHASE(ii, p) {                                                         \
      v2f g1 = FMA2(ug[ii][0], vg0, FMA2(ug[ii][1], vg1,                           \
                FMA2(ug[ii][2], vg2v, su[ii] + sv)));                              \
      v2f d1 = u1[ii] - v1;                                                        \
      v2f n1 = d1 * d1;                                                            \
      v2f x1 = FMA2(c11[ii] * g21, Av1, Bv1);                                      \
      v2f t1, P1;                                                                  \
      t1.x = __builtin_amdgcn_exp2f(x1.x); t1.y = __builtin_amdgcn_exp2f(x1.y);    \
      P1.x = __builtin_amdgcn_rcpf(1.0f + t1.x); P1.y = __builtin_amdgcn_rcpf(1.0f + t1.y); \
      v2f h1 = FMA2(P1, n1 - g1, g1);                                              \
      hb[4 * lane + (p)]     = h1.x;                                               \
      hb[4 * lane + 2 + (p)] = h1.y;                                               \
    }

  // CONSUME for output ii using component p of the shared b64 gather results
  #define CONSUME(ii, p) {                                                         \
      v2f g2;                                                                      \
      g2.x = ((p) ? r0.y : r0.x) * W2[0].x + ((p) ? r1.y : r1.x) * W2[1].x         \
           + ((p) ? r2.y : r2.x) * W2[2].x;                                        \
      g2.y = ((p) ? r3.y : r3.x) * W2[0].y + ((p) ? r4.y : r4.x) * W2[1].y         \
           + ((p) ? r5.y : r5.x) * W2[2].y;                                        \
      v2f d2 = u2[ii] - v2;                                                        \
      v2f n2 = d2 * d2;                                                            \
      v2f x2 = FMA2(c12[ii] * g22, Av2, Bv2);                                      \
      v2f t2, P2;                                                                  \
      t2.x = __builtin_amdgcn_exp2f(x2.x); t2.y = __builtin_amdgcn_exp2f(x2.y);    \
      P2.x = __builtin_amdgcn_rcpf(1.0f + t2.x); P2.y = __builtin_amdgcn_rcpf(1.0f + t2.y); \
      v2f h2 = FMA2(P2, n2 - g2, g2);                                              \
      float s = dpp_wave_sum_lane63(h2.x + h2.y);                                  \
      if (lane == 63) out[(i0 + ii) * BB + j] = s;                                 \
    }

  #define PAIR(iA, iB) {                                                           \
      H1PHASE(iA, 0)                                                               \
      H1PHASE(iB, 1)                                                               \
      float2 r0 = hb2[I2[0][0]], r1 = hb2[I2[1][0]], r2 = hb2[I2[2][0]];           \
      float2 r3 = hb2[I2[0][1]], r4 = hb2[I2[1][1]], r5 = hb2[I2[2][1]];           \
      CONSUME(iA, 0)                                                               \
      CONSUME(iB, 1)                                                               \
    }

  #pragma unroll 1
  for (int jj = 0; jj < 8; ++jj) {
    const int j = j0 + jj;
    v2f vg0  = LD2(VGp, (j * 3 + 0) * HD + lane);
    v2f vg1  = LD2(VGp, (j * 3 + 1) * HD + lane);
    v2f vg2v = LD2(VGp, (j * 3 + 2) * HD + lane);
    v2f sv   = LD2(SVp, j * HD + lane);
    const v2f v1  = LD2(E2p, (1 * BB + j) * HD + lane);
    const v2f v2  = LD2(E2p, (2 * BB + j) * HD + lane);
    const v2f g21 = LD2(C2p, (0 * BB + j) * HD + lane);
    const v2f g22 = LD2(C2p, (1 * BB + j) * HD + lane);

    PAIR(0, 1)
    PAIR(2, 3)
  }
  #undef H1PHASE
  #undef CONSUME
  #undef PAIR
}

extern "C" void kernel_launch(void* const* d_in, const int* in_sizes, int n_in,
                              void* d_out, int out_size, void* d_ws, size_t ws_size,
                              hipStream_t stream) {
  (void)in_sizes; (void)n_in; (void)out_size; (void)ws_size;
  // dict order: [0]emb1_0 [1]emb2_0 [2]cert1_0 [3]cert2_0 [4]alpha_0 [5]beta_0
  //             [6..11] layer1, [12..17] layer2, [18]link_0 [19]link_1
  float* ws = (float*)d_ws;
  PackArgs pa;
  pa.src[0] = (const float*)d_in[0];  pa.src[1] = (const float*)d_in[6];  pa.src[2] = (const float*)d_in[12];
  pa.src[3] = (const float*)d_in[1];  pa.src[4] = (const float*)d_in[7];  pa.src[5] = (const float*)d_in[13];
  pa.src[6] = (const float*)d_in[8];  pa.src[7] = (const float*)d_in[14];
  pa.src[8] = (const float*)d_in[9];  pa.src[9] = (const float*)d_in[15];
  hipLaunchKernelGGL(prep_kernel, dim3(1344), dim3(256), 0, stream, pa,
                     (const float*)d_in[18], (const float*)d_in[19],
                     (const float*)d_in[10], (const float*)d_in[11],
                     (const float*)d_in[16], (const float*)d_in[17], ws);
  hipLaunchKernelGGL(prep2_kernel, dim3(256), dim3(256), 0, stream, ws);
  hipLaunchKernelGGL(main_kernel, dim3(2048), dim3(256), 0, stream,
                     (const float*)ws, (float*)d_out);
}